// Round 9
// baseline (142.410 us; speedup 1.0000x reference)
//
#include <hip/hip_runtime.h>
#include <hip/hip_bf16.h>
#include <float.h>

// Problem constants (fixed by setup_inputs)
constexpr int B = 8, N = 4096, M = 4096, E = 12288;
constexpr int CBLOCK = 1024;                  // threads per block
constexpr int EDGE_BLOCKS = (B * E) / CBLOCK; // 96 (first in grid; short-lived)
constexpr int CHAM_BLOCKS = 2 * B * (N / 256);// 256 (2 dir x 8 b x 16 qtiles)
constexpr int SPLIT = 64;                     // ref-sweep split across thread groups
constexpr int RPT = M / SPLIT;                // 64 refs per thread
constexpr int VEC = 16;                       // register queries per thread
constexpr int QB = 256;                       // queries per block
constexpr int NPASS = 4;                      // DIAGNOSTIC: idempotent sweep x4

// ws layout (floats): [0..192) edge per-block (sumL,sumL2) pairs,
//                     [192..192+256) chamfer per-block sqrt-sums.
// Every slot written unconditionally -> 0xAA poison harmless, no init kernel.

__global__ __launch_bounds__(CBLOCK) void fused_kernel(
    const float* __restrict__ pred, const float* __restrict__ gt,
    const int* __restrict__ edges, float* __restrict__ ws) {
    const int bid = blockIdx.x;
    const int t = threadIdx.x;

    __shared__ float4 tile[M];                // 64 KB: refs {x,y,z,0.5|p|^2}
    __shared__ float wsum[16];
    float* red = (float*)tile;                // aliased [SPLIT][QB]: tile dead first

    if (bid >= EDGE_BLOCKS) {
        // ---------------- chamfer block ----------------
        const int cb  = bid - EDGE_BLOCKS;    // 0..255
        const int dir = cb >> 7;              // 0: q=pred/ref=gt, 1: swapped
        const int b   = (cb >> 4) & 7;
        const int qt  = cb & 15;
        const float* __restrict__ q   = dir ? gt   : pred;
        const float* __restrict__ ref = dir ? pred : gt;

        // stage ALL M ref points: thread t loads points 4t..4t+3 (6 coalesced float2)
        {
            const float2* rb = (const float2*)(ref + (size_t)b * M * 3) + 6 * t;
            const float2 r0 = rb[0], r1 = rb[1], r2 = rb[2];
            const float2 r3 = rb[3], r4 = rb[4], r5 = rb[5];
            const float x0=r0.x,y0=r0.y,z0=r1.x, x1=r1.y,y1=r2.x,z1=r2.y;
            const float x2=r3.x,y2=r3.y,z2=r4.x, x3=r4.y,y3=r5.x,z3=r5.y;
            tile[4*t+0] = make_float4(x0,y0,z0, 0.5f*(x0*x0+y0*y0+z0*z0));
            tile[4*t+1] = make_float4(x1,y1,z1, 0.5f*(x1*x1+y1*y1+z1*z1));
            tile[4*t+2] = make_float4(x2,y2,z2, 0.5f*(x2*x2+y2*y2+z2*z2));
            tile[4*t+3] = make_float4(x3,y3,z3, 0.5f*(x3*x3+y3*y3+z3*z3));
        }

        // this thread's VEC=16 register queries (|q|^2 handled in the tail)
        const int qloc = t & 15;              // 0..15
        const int s    = t >> 4;              // 0..63 -> ref segment
        float qx[VEC], qy[VEC], qz[VEC];
#pragma unroll
        for (int i = 0; i < VEC; i++) {
            const int n = qt * QB + qloc + i * 16;
            const float* qp = q + ((size_t)b * N + n) * 3;
            qx[i] = qp[0]; qy[i] = qp[1]; qz[i] = qp[2];
        }
        __syncthreads();

        const float4* tl = tile + s * RPT;
        float mn[VEC];
#pragma unroll
        for (int i = 0; i < VEC; i++) mn[i] = FLT_MAX;

        // DIAGNOSTIC: sweep the SAME segment NPASS times (min is idempotent).
        // Alternating direction + asm fences block CSE between passes.
        for (int pass = 0; pass < NPASS; ++pass) {
            const bool rev = pass & 1;
#pragma unroll 2
            for (int mm = 0; mm < RPT; mm += 2) {
                const int m = rev ? (RPT - 2 - mm) : mm;
                const float4 pA = tl[m], pB = tl[m + 1];
#pragma unroll
                for (int i = 0; i < VEC; i++) {
                    float d0 = fmaf(-qz[i], pA.z, pA.w);
                    d0 = fmaf(-qy[i], pA.y, d0);
                    d0 = fmaf(-qx[i], pA.x, d0);
                    float d1 = fmaf(-qz[i], pB.z, pB.w);
                    d1 = fmaf(-qy[i], pB.y, d1);
                    d1 = fmaf(-qx[i], pB.x, d1);
                    mn[i] = fminf(mn[i], fminf(d0, d1));   // -> v_min3_f32
                }
            }
#pragma unroll
            for (int i = 0; i < VEC; i++)
                asm volatile("" : "+v"(mn[i]));            // keep live, block CSE
        }
        __syncthreads();                      // tile dead; red alias live

        // seg-major partials: red[s][q]
#pragma unroll
        for (int i = 0; i < VEC; i++)
            red[s * QB + qloc + i * 16] = mn[i];
        __syncthreads();

        float sv = 0.0f;
        if (t < QB) {
            float m = red[t];                 // conflict-free column reads
#pragma unroll 8
            for (int k = 1; k < SPLIT; k++) m = fminf(m, red[k * QB + t]);
            // add back |q|^2: d = sqrt(max(2*m + |q|^2, 0))
            const float* qp = q + ((size_t)b * N + qt * QB + t) * 3;
            const float sq = qp[0]*qp[0] + qp[1]*qp[1] + qp[2]*qp[2];
            sv = sqrtf(fmaxf(2.0f * m + sq, 0.0f));
        }
#pragma unroll
        for (int o = 32; o > 0; o >>= 1) sv += __shfl_down(sv, o, 64);
        if ((t & 63) == 0) wsum[t >> 6] = sv;
        __syncthreads();
        if (t == 0)
            ws[2 * EDGE_BLOCKS + cb] = wsum[0] + wsum[1] + wsum[2] + wsum[3];
    } else {
        // ---------------- edge-length block ----------------
        const int eg = bid * CBLOCK + t;      // 0..98303
        const int b  = eg / E;
        const int e  = eg - b * E;
        const int i0 = edges[2 * e], i1 = edges[2 * e + 1];
        const float* p0 = pred + ((size_t)b * N + i0) * 3;
        const float* p1 = pred + ((size_t)b * N + i1) * 3;
        const float dx = p0[0] - p1[0];
        const float dy = p0[1] - p1[1];
        const float dz = p0[2] - p1[2];
        float L  = sqrtf(dx * dx + dy * dy + dz * dz);
        float L2 = L * L;
#pragma unroll
        for (int o = 32; o > 0; o >>= 1) {
            L  += __shfl_down(L, o, 64);
            L2 += __shfl_down(L2, o, 64);
        }
        if ((t & 63) == 0) { red[t >> 6] = L; red[32 + (t >> 6)] = L2; }
        __syncthreads();
        if (t == 0) {
            float a = 0.0f, c = 0.0f;
#pragma unroll
            for (int w = 0; w < 16; w++) { a += red[w]; c += red[32 + w]; }
            ws[2 * bid]     = a;
            ws[2 * bid + 1] = c;
        }
    }
}

__global__ __launch_bounds__(256) void final_kernel(
    const float* __restrict__ ws, float* __restrict__ out) {
    const int t = threadIdx.x;
    float sc = ws[2 * EDGE_BLOCKS + t];       // 256 chamfer partials
    float s1 = 0.0f, s2 = 0.0f;
    if (t < EDGE_BLOCKS) {
        s1 = ws[2 * t];
        s2 = ws[2 * t + 1];
    }
#pragma unroll
    for (int o = 32; o > 0; o >>= 1) {
        sc += __shfl_down(sc, o, 64);
        s1 += __shfl_down(s1, o, 64);
        s2 += __shfl_down(s2, o, 64);
    }
    __shared__ float w[3][4];
    const int wv = t >> 6, ln = t & 63;
    if (ln == 0) { w[0][wv] = sc; w[1][wv] = s1; w[2][wv] = s2; }
    __syncthreads();
    if (t == 0) {
        float S = 0.0f, A = 0.0f, C = 0.0f;
#pragma unroll
        for (int i = 0; i < 4; i++) { S += w[0][i]; A += w[1][i]; C += w[2][i]; }
        const float K = (float)(B * E);       // 98304
        const float var = (C - A * A / K) / (K - 1.0f);
        out[0] = S / 32768.0f + 0.1f * var;   // cd + 0.1 * edge_var
    }
}

extern "C" void kernel_launch(void* const* d_in, const int* in_sizes, int n_in,
                              void* d_out, int out_size, void* d_ws, size_t ws_size,
                              hipStream_t stream) {
    const float* pred  = (const float*)d_in[0];
    const float* gt    = (const float*)d_in[1];
    const int*   edges = (const int*)d_in[2];
    float* out = (float*)d_out;
    float* wsf = (float*)d_ws;

    fused_kernel<<<EDGE_BLOCKS + CHAM_BLOCKS, CBLOCK, 0, stream>>>(pred, gt, edges, wsf);
    final_kernel<<<1, 256, 0, stream>>>(wsf, out);
}

// Round 10
// 82.214 us; speedup vs baseline: 1.7322x; 1.7322x over previous
//
#include <hip/hip_runtime.h>
#include <hip/hip_bf16.h>
#include <float.h>

// Problem constants (fixed by setup_inputs)
constexpr int B = 8, N = 4096, M = 4096, E = 12288;
constexpr int TB = 512;                       // threads per block
constexpr int EDGE_BLOCKS = (B * E) / TB;     // 192 (first in grid)
constexpr int QB = 256;                       // queries per chamfer block
constexpr int CHAM_BLOCKS = 2 * B * (N / QB); // 256
constexpr int SPLIT = 32;                     // ref segments per block
constexpr int RPT = M / SPLIT;                // 128 refs per segment
constexpr int VEC = 16;                       // queries per thread (8 packed pairs)
constexpr int SEGSTRIDE = RPT + 1;            // 129 float4 -> banks rotate 4/segment
constexpr int REDSTRIDE = QB + 4;             // 260 floats -> banks rotate 4/segment

// ws layout (floats): [0..384) edge per-block (sumL,sumL2) pairs,
//                     [384..640) chamfer per-block sqrt-sums.
// Every slot written unconditionally -> 0xAA poison harmless, no init kernel.

__global__ __launch_bounds__(TB, 4) void fused_kernel(
    const float* __restrict__ pred, const float* __restrict__ gt,
    const int* __restrict__ edges, float* __restrict__ ws) {
    const int bid = blockIdx.x;
    const int t = threadIdx.x;

    __shared__ float4 tile[SPLIT * SEGSTRIDE];   // 66048 B, skewed segments
    __shared__ float wsum[8], wsum2[8];
    float* red = (float*)tile;                   // aliased [SPLIT][REDSTRIDE]

    if (bid >= EDGE_BLOCKS) {
        // ---------------- chamfer block ----------------
        const int cb  = bid - EDGE_BLOCKS;       // 0..255
        const int dir = cb >> 7;                 // 0: q=pred/ref=gt, 1: swapped
        const int b   = (cb >> 4) & 7;
        const int qt  = cb & 15;
        const float* __restrict__ q   = dir ? gt   : pred;
        const float* __restrict__ ref = dir ? pred : gt;

        // stage all M refs, skewed: thread t writes points g = t + 512*r
        {
            const float* rb = ref + (size_t)b * M * 3;
#pragma unroll
            for (int r = 0; r < M / TB; ++r) {
                const int g = t + TB * r;
                const float x = rb[3 * g], y = rb[3 * g + 1], z = rb[3 * g + 2];
                tile[(g >> 7) * SEGSTRIDE + (g & 127)] =
                    make_float4(x, y, z, 0.5f * (x * x + y * y + z * z));
            }
        }

        // this thread's VEC=16 queries, pre-negated, packed in pairs
        const int qloc = t & 15;                 // 0..15
        const int s    = t >> 4;                 // 0..31 -> ref segment
        float2 nqx2[8], nqy2[8], nqz2[8];
#pragma unroll
        for (int j = 0; j < 8; ++j) {
            const int n0 = qt * QB + qloc + (2 * j) * 16;
            const float* q0 = q + ((size_t)b * N + n0) * 3;
            const float* q1 = q0 + 48;           // n0 + 16 queries
            nqx2[j] = make_float2(-q0[0], -q1[0]);
            nqy2[j] = make_float2(-q0[1], -q1[1]);
            nqz2[j] = make_float2(-q0[2], -q1[2]);
        }
        __syncthreads();

        const float4* tl = tile + s * SEGSTRIDE;
        float mn[VEC];
#pragma unroll
        for (int i = 0; i < VEC; i++) mn[i] = FLT_MAX;

        // sweep: per 2 points x 16 queries = 48 v_pk_fma_f32 + 16 v_min3_f32
#pragma unroll 2
        for (int m = 0; m < RPT; m += 2) {
            const float4 a  = tl[m];
            const float4 bb = tl[m + 1];
            const float2 axy = make_float2(a.x, a.y),  azw = make_float2(a.z, a.w);
            const float2 bxy = make_float2(bb.x, bb.y), bzw = make_float2(bb.z, bb.w);
#pragma unroll
            for (int j = 0; j < 8; ++j) {
                float2 ta, tc;
                // ta = { w - q.p } for queries 2j, 2j+1 against point a
                asm("v_pk_fma_f32 %0, %1, %2, %1 op_sel:[0,0,1] op_sel_hi:[0,1,1]"
                    : "=v"(ta) : "v"(azw), "v"(nqz2[j]));          // z*(-qz) + w
                asm("v_pk_fma_f32 %0, %1, %2, %0 op_sel:[1,0,0] op_sel_hi:[1,1,1]"
                    : "+v"(ta) : "v"(axy), "v"(nqy2[j]));          // + y*(-qy)
                asm("v_pk_fma_f32 %0, %1, %2, %0 op_sel:[0,0,0] op_sel_hi:[0,1,1]"
                    : "+v"(ta) : "v"(axy), "v"(nqx2[j]));          // + x*(-qx)
                asm("v_pk_fma_f32 %0, %1, %2, %1 op_sel:[0,0,1] op_sel_hi:[0,1,1]"
                    : "=v"(tc) : "v"(bzw), "v"(nqz2[j]));
                asm("v_pk_fma_f32 %0, %1, %2, %0 op_sel:[1,0,0] op_sel_hi:[1,1,1]"
                    : "+v"(tc) : "v"(bxy), "v"(nqy2[j]));
                asm("v_pk_fma_f32 %0, %1, %2, %0 op_sel:[0,0,0] op_sel_hi:[0,1,1]"
                    : "+v"(tc) : "v"(bxy), "v"(nqx2[j]));
                asm("v_min3_f32 %0, %0, %1, %2"
                    : "+v"(mn[2 * j])     : "v"(ta.x), "v"(tc.x));
                asm("v_min3_f32 %0, %0, %1, %2"
                    : "+v"(mn[2 * j + 1]) : "v"(ta.y), "v"(tc.y));
            }
        }
        __syncthreads();                         // tile dead; red alias live

        // seg-major partials red[s][q], skewed
#pragma unroll
        for (int i = 0; i < VEC; i++)
            red[s * REDSTRIDE + qloc + i * 16] = mn[i];
        __syncthreads();

        float sv = 0.0f;
        if (t < QB) {
            float m = red[t];                    // consecutive lanes: conflict-free
#pragma unroll 8
            for (int k = 1; k < SPLIT; k++) m = fminf(m, red[k * REDSTRIDE + t]);
            const float* qp = q + ((size_t)b * N + qt * QB + t) * 3;
            const float sq = qp[0] * qp[0] + qp[1] * qp[1] + qp[2] * qp[2];
            sv = sqrtf(fmaxf(2.0f * m + sq, 0.0f));   // + |q|^2, back to distance
        }
#pragma unroll
        for (int o = 32; o > 0; o >>= 1) sv += __shfl_down(sv, o, 64);
        if ((t & 63) == 0) wsum[t >> 6] = sv;
        __syncthreads();
        if (t == 0)
            ws[2 * EDGE_BLOCKS + cb] = wsum[0] + wsum[1] + wsum[2] + wsum[3];
    } else {
        // ---------------- edge-length block ----------------
        const int eg = bid * TB + t;             // 0..98303
        const int b  = eg / E;
        const int e  = eg - b * E;
        const int i0 = edges[2 * e], i1 = edges[2 * e + 1];
        const float* p0 = pred + ((size_t)b * N + i0) * 3;
        const float* p1 = pred + ((size_t)b * N + i1) * 3;
        const float dx = p0[0] - p1[0];
        const float dy = p0[1] - p1[1];
        const float dz = p0[2] - p1[2];
        float L  = sqrtf(dx * dx + dy * dy + dz * dz);
        float L2 = L * L;
#pragma unroll
        for (int o = 32; o > 0; o >>= 1) {
            L  += __shfl_down(L, o, 64);
            L2 += __shfl_down(L2, o, 64);
        }
        const int wv = t >> 6;
        if ((t & 63) == 0) { wsum[wv] = L; wsum2[wv] = L2; }
        __syncthreads();
        if (t == 0) {
            float a = 0.0f, c = 0.0f;
#pragma unroll
            for (int w = 0; w < 8; w++) { a += wsum[w]; c += wsum2[w]; }
            ws[2 * bid]     = a;
            ws[2 * bid + 1] = c;
        }
    }
}

__global__ __launch_bounds__(256) void final_kernel(
    const float* __restrict__ ws, float* __restrict__ out) {
    const int t = threadIdx.x;
    float sc = ws[2 * EDGE_BLOCKS + t];          // 256 chamfer partials
    float s1 = 0.0f, s2 = 0.0f;
    if (t < EDGE_BLOCKS) {                       // 192 edge pairs
        s1 = ws[2 * t];
        s2 = ws[2 * t + 1];
    }
#pragma unroll
    for (int o = 32; o > 0; o >>= 1) {
        sc += __shfl_down(sc, o, 64);
        s1 += __shfl_down(s1, o, 64);
        s2 += __shfl_down(s2, o, 64);
    }
    __shared__ float w[3][4];
    const int wv = t >> 6, ln = t & 63;
    if (ln == 0) { w[0][wv] = sc; w[1][wv] = s1; w[2][wv] = s2; }
    __syncthreads();
    if (t == 0) {
        float S = 0.0f, A = 0.0f, C = 0.0f;
#pragma unroll
        for (int i = 0; i < 4; i++) { S += w[0][i]; A += w[1][i]; C += w[2][i]; }
        const float K = (float)(B * E);          // 98304
        const float var = (C - A * A / K) / (K - 1.0f);
        out[0] = S / 32768.0f + 0.1f * var;      // cd + 0.1 * edge_var
    }
}

extern "C" void kernel_launch(void* const* d_in, const int* in_sizes, int n_in,
                              void* d_out, int out_size, void* d_ws, size_t ws_size,
                              hipStream_t stream) {
    const float* pred  = (const float*)d_in[0];
    const float* gt    = (const float*)d_in[1];
    const int*   edges = (const int*)d_in[2];
    float* out = (float*)d_out;
    float* wsf = (float*)d_ws;

    fused_kernel<<<EDGE_BLOCKS + CHAM_BLOCKS, TB, 0, stream>>>(pred, gt, edges, wsf);
    final_kernel<<<1, 256, 0, stream>>>(wsf, out);
}